// Round 15
// baseline (59.576 us; speedup 1.0000x reference)
//
#include <hip/hip_runtime.h>
#include <hip/hip_bf16.h>

#define DIM   768
#define NH    12
#define HD    64
#define BB    2
#define SS    2048
#define QKVN  (3 * DIM)   // 2304
#define MM    (BB * SS)   // 4096

typedef __attribute__((ext_vector_type(8))) short bf16x8;
typedef __attribute__((ext_vector_type(8))) short short8;
typedef __attribute__((ext_vector_type(4))) float f32x4;

__device__ __forceinline__ short f2bf(float f) {
    unsigned int u = __float_as_uint(f);
    unsigned int r = (u + 0x7FFFu + ((u >> 16) & 1u)) >> 16;
    return (short)r;
}
__device__ __forceinline__ float bf2f(short s) {
    return __uint_as_float((unsigned int)(unsigned short)s << 16);
}

__device__ __forceinline__ void gld16(const short* g, short* l) {
    __builtin_amdgcn_global_load_lds(
        (const __attribute__((address_space(1))) void*)g,
        (__attribute__((address_space(3))) void*)l, 16, 0, 0);
}

template<int N> __device__ __forceinline__ void waitvm() {
    if constexpr (N == 0) asm volatile("s_waitcnt vmcnt(0)" ::: "memory");
    else if constexpr (N == 3) asm volatile("s_waitcnt vmcnt(3)" ::: "memory");
    else if constexpr (N == 4) asm volatile("s_waitcnt vmcnt(4)" ::: "memory");
}

// fp32 -> bf16 conversion for x, w_qkv, w_out (R8-exact)
__global__ __launch_bounds__(256) void conv_kernel(
    const float* __restrict__ x,  short* __restrict__ xb,
    const float* __restrict__ wq, short* __restrict__ wqb,
    const float* __restrict__ wo, short* __restrict__ wob)
{
    const int nx = (MM * DIM) / 8;
    const int nq = (QKVN * DIM) / 8;
    int i8 = blockIdx.x * 256 + threadIdx.x;
    const float* src; short* dst;
    if (i8 < nx)           { src = x;  dst = xb; }
    else if (i8 < nx + nq) { i8 -= nx; src = wq; dst = wqb; }
    else                   { i8 -= nx + nq; src = wo; dst = wob; }
    const float4* p = (const float4*)src + (size_t)i8 * 2;
    float4 a = p[0], b = p[1];
    short8 r;
    r[0] = f2bf(a.x); r[1] = f2bf(a.y); r[2] = f2bf(a.z); r[3] = f2bf(a.w);
    r[4] = f2bf(b.x); r[5] = f2bf(b.y); r[6] = f2bf(b.z); r[7] = f2bf(b.w);
    *((short8*)dst + i8) = r;
}

// ------------- GEMM core: counted-vmcnt 2-buffer pipeline (R8-exact) -----

template<int RT>
__device__ __forceinline__ void stage_op(const short* gb, int K, int k0, short* ld)
{
#pragma unroll
    for (int ii = 0; ii < RT / 64; ++ii)
        gld16(gb + (size_t)(64 * ii) * K + k0, ld + ii * 4096);
}

template<int MF, int NF>
__device__ __forceinline__ void read_frags(
    const short* lsA, const short* lsB, int arow, int brow, int kg, int sw,
    bf16x8 af[2][MF], bf16x8 bfr[2][NF])
{
#pragma unroll
    for (int kk = 0; kk < 2; ++kk) {
        const int ko = (kk * 32 + kg * 8) ^ sw;
#pragma unroll
        for (int i = 0; i < MF; ++i)
            af[kk][i] = *(const bf16x8*)&lsA[(arow + i * 16) * 64 + ko];
#pragma unroll
        for (int j = 0; j < NF; ++j)
            bfr[kk][j] = *(const bf16x8*)&lsB[(brow + j * 16) * 64 + ko];
    }
}

template<int MF, int NF>
__device__ __forceinline__ void mfma_frags(
    bf16x8 af[2][MF], bf16x8 bfr[2][NF], f32x4 acc[MF][NF])
{
#pragma unroll
    for (int kk = 0; kk < 2; ++kk)
#pragma unroll
        for (int i = 0; i < MF; ++i)
#pragma unroll
            for (int j = 0; j < NF; ++j)
                acc[i][j] = __builtin_amdgcn_mfma_f32_16x16x32_bf16(
                    af[kk][i], bfr[kk][j], acc[i][j], 0, 0, 0);
}

template<int MF, int NF, int ART, int BRT, int VC>
__device__ __forceinline__ void phase_steady(
    const short* lsA, const short* lsB, short* ldA, short* ldB,
    const short* Ab, const short* Bb, int K, int knext,
    int arow, int brow, int kg, int sw, f32x4 acc[MF][NF])
{
    bf16x8 af[2][MF], bfr[2][NF];
    read_frags<MF, NF>(lsA, lsB, arow, brow, kg, sw, af, bfr);
    asm volatile("s_waitcnt lgkmcnt(0)" ::: "memory");
    __builtin_amdgcn_s_barrier();
    stage_op<ART>(Ab, K, knext, ldA);
    stage_op<BRT>(Bb, K, knext, ldB);
    mfma_frags<MF, NF>(af, bfr, acc);
    waitvm<VC>();
    __builtin_amdgcn_s_barrier();
}

// GEMM1: BM=128, BN=128, 512 thr (8 waves 2x4), MF=4, NF=2. K=768 (NT=12).
__global__ __launch_bounds__(512) void gemm_qkv_kernel(
    const short* __restrict__ A, const short* __restrict__ Bm,
    const float* __restrict__ bias, short* __restrict__ qkvh)
{
    constexpr int K = DIM, NT = 12;
    __shared__ short lsA0[8192], lsB0[8192], lsA1[8192], lsB1[8192];

    const int t    = threadIdx.x;
    const int lane = t & 63;
    const int wid  = t >> 6;
    const int wrow = wid >> 2, wcol = wid & 3;
    const int l16  = lane & 15;
    const int kg   = lane >> 4;
    const int row0 = blockIdx.y * 128;
    const int col0 = blockIdx.x * 128;

    const int srow = t >> 3;
    const int scol = ((t & 7) ^ (srow & 7)) * 8;
    const short* Ab = A  + (size_t)(row0 + srow) * K + scol;
    const short* Bb = Bm + (size_t)(col0 + srow) * K + scol;
    short* ldA0 = lsA0 + t * 8;  short* ldB0 = lsB0 + t * 8;
    short* ldA1 = lsA1 + t * 8;  short* ldB1 = lsB1 + t * 8;
    const int arow = wrow * 64 + l16;
    const int brow = wcol * 32 + l16;
    const int sw   = (l16 & 7) * 8;

    f32x4 acc[4][2];
#pragma unroll
    for (int i = 0; i < 4; ++i)
#pragma unroll
        for (int j = 0; j < 2; ++j) acc[i][j] = (f32x4){0.f, 0.f, 0.f, 0.f};

    stage_op<128>(Ab, K, 0, ldA0);
    stage_op<128>(Bb, K, 0, ldB0);
    stage_op<128>(Ab, K, 64, ldA1);
    stage_op<128>(Bb, K, 64, ldB1);
    waitvm<4>();
    __builtin_amdgcn_s_barrier();

#pragma unroll
    for (int kt = 0; kt < NT - 2; kt += 2) {
        phase_steady<4, 2, 128, 128, 4>(lsA0, lsB0, ldA0, ldB0, Ab, Bb, K,
                                        (kt + 2) * 64, arow, brow, kg, sw, acc);
        phase_steady<4, 2, 128, 128, 4>(lsA1, lsB1, ldA1, ldB1, Ab, Bb, K,
                                        (kt + 3) * 64, arow, brow, kg, sw, acc);
    }
    {
        bf16x8 af[2][4], bfr[2][2];
        read_frags<4, 2>(lsA0, lsB0, arow, brow, kg, sw, af, bfr);
        mfma_frags<4, 2>(af, bfr, acc);
        waitvm<0>();
        __builtin_amdgcn_s_barrier();
        read_frags<4, 2>(lsA1, lsB1, arow, brow, kg, sw, af, bfr);
        mfma_frags<4, 2>(af, bfr, acc);
    }

#pragma unroll
    for (int j = 0; j < 2; ++j) {
        const int col = col0 + wcol * 32 + j * 16 + l16;
        const int ty = col / DIM;
        const int hh = (col % DIM) >> 6;
        const int dd = col & 63;
        const float bv = bias[col];
        const size_t cbase = ((size_t)(ty * BB * NH) * SS) * HD;
#pragma unroll
        for (int i = 0; i < 4; ++i) {
            const int rbase = row0 + wrow * 64 + i * 16 + kg * 4;
#pragma unroll
            for (int r = 0; r < 4; ++r) {
                const int row = rbase + r;
                const int bq = row >> 11, sq = row & 2047;
                qkvh[cbase + (((size_t)(bq * NH + hh) * SS + sq) << 6) + dd] =
                    f2bf(acc[i][j][r] + bv);
            }
        }
    }
}

// GEMM2: BM=64, BN=128, 512 thr, MF=2, NF=2 (grid 6x64=384). NT=12. R8-exact.
__global__ __launch_bounds__(512) void gemm_out_kernel(
    const short* __restrict__ A, const short* __restrict__ Bm,
    const float* __restrict__ bias, float* __restrict__ C)
{
    constexpr int K = DIM, N = DIM, NT = 12;
    __shared__ short lsA0[4096], lsB0[8192], lsA1[4096], lsB1[8192];

    const int t    = threadIdx.x;
    const int lane = t & 63;
    const int wid  = t >> 6;
    const int wrow = wid >> 2, wcol = wid & 3;
    const int l16  = lane & 15;
    const int kg   = lane >> 4;
    const int row0 = blockIdx.y * 64;
    const int col0 = blockIdx.x * 128;

    const int srow = t >> 3;
    const int scol = ((t & 7) ^ (srow & 7)) * 8;
    const short* Ab = A  + (size_t)(row0 + srow) * K + scol;
    const short* Bb = Bm + (size_t)(col0 + srow) * K + scol;
    short* ldA0 = lsA0 + t * 8;  short* ldB0 = lsB0 + t * 8;
    short* ldA1 = lsA1 + t * 8;  short* ldB1 = lsB1 + t * 8;
    const int arow = wrow * 32 + l16;
    const int brow = wcol * 32 + l16;
    const int sw   = (l16 & 7) * 8;

    f32x4 acc[2][2];
#pragma unroll
    for (int i = 0; i < 2; ++i)
#pragma unroll
        for (int j = 0; j < 2; ++j) acc[i][j] = (f32x4){0.f, 0.f, 0.f, 0.f};

    stage_op<64>(Ab, K, 0, ldA0);
    stage_op<128>(Bb, K, 0, ldB0);
    stage_op<64>(Ab, K, 64, ldA1);
    stage_op<128>(Bb, K, 64, ldB1);
    waitvm<3>();
    __builtin_amdgcn_s_barrier();

#pragma unroll
    for (int kt = 0; kt < NT - 2; kt += 2) {
        phase_steady<2, 2, 64, 128, 3>(lsA0, lsB0, ldA0, ldB0, Ab, Bb, K,
                                       (kt + 2) * 64, arow, brow, kg, sw, acc);
        phase_steady<2, 2, 64, 128, 3>(lsA1, lsB1, ldA1, ldB1, Ab, Bb, K,
                                       (kt + 3) * 64, arow, brow, kg, sw, acc);
    }
    {
        bf16x8 af[2][2], bfr[2][2];
        read_frags<2, 2>(lsA0, lsB0, arow, brow, kg, sw, af, bfr);
        mfma_frags<2, 2>(af, bfr, acc);
        waitvm<0>();
        __builtin_amdgcn_s_barrier();
        read_frags<2, 2>(lsA1, lsB1, arow, brow, kg, sw, af, bfr);
        mfma_frags<2, 2>(af, bfr, acc);
    }

#pragma unroll
    for (int j = 0; j < 2; ++j) {
        const int col = col0 + wcol * 32 + j * 16 + l16;
        const float bv = bias[col];
#pragma unroll
        for (int i = 0; i < 2; ++i) {
            const int rbase = row0 + wrow * 32 + i * 16 + kg * 4;
#pragma unroll
            for (int r = 0; r < 4; ++r)
                C[(size_t)(rbase + r) * N + col] = acc[i][j][r] + bv;
        }
    }
}

// Sparse Fibonacci attention — R14 (dot2) + R15 wave-uniform early-skip:
// per wave, s in [base, base+8); rows with fib[f] > smax are skipped entirely
// (scalar branch: no K/V load, no dot2, no shuffles). ~13% avg work cut.
__global__ __launch_bounds__(256) void fib_attn_kernel(
    const short* __restrict__ qkvh, short* __restrict__ attn)
{
    const int idx   = blockIdx.x;          // [0,1536)
    const int j     = idx >> 3;            // [0,192)
    const int bh    = (idx & 7) + 8 * (j >> 6);   // [0,24), pinned per XCD
    const int chunk = j & 63;              // [0,64)
    const int wid   = threadIdx.x >> 6;
    const int lane  = threadIdx.x & 63;
    const int ql    = lane >> 3;
    const int c     = lane & 7;
    const int s     = chunk * 32 + wid * 8 + ql;
    const int smax  = chunk * 32 + wid * 8 + 7;   // wave-uniform
    const int b = bh / NH, h = bh % NH;

    constexpr size_t TYB = (size_t)BB * NH * SS * HD;
    const size_t base = ((size_t)bh * SS) << 6;
    const short* Kp = qkvh + TYB + base;
    const short* Vp = qkvh + 2 * TYB + base;

    // q as 4 packed bf16-pair words (feeds dot2 directly)
    const int4 qp = *(const int4*)(qkvh + base + ((size_t)s << 6) + c * 8);

    constexpr int NF = 17;
    const int fib[NF] = {0, 1, 2, 3, 5, 8, 13, 21, 34, 55, 89, 144,
                         233, 377, 610, 987, 1597};
    float sc[NF];
#pragma unroll
    for (int f = 0; f < NF; ++f) {
        if (fib[f] > smax) { sc[f] = -1e30f; continue; }   // wave-uniform skip
        const bool ok = (fib[f] <= s);
        const int sk = ok ? s - fib[f] : s;
        const int4 kv = *(const int4*)(Kp + ((size_t)sk << 6) + c * 8);
        float part = 0.f;
        asm("v_dot2_f32_bf16 %0, %1, %2, %0" : "+v"(part) : "v"(kv.x), "v"(qp.x));
        asm("v_dot2_f32_bf16 %0, %1, %2, %0" : "+v"(part) : "v"(kv.y), "v"(qp.y));
        asm("v_dot2_f32_bf16 %0, %1, %2, %0" : "+v"(part) : "v"(kv.z), "v"(qp.z));
        asm("v_dot2_f32_bf16 %0, %1, %2, %0" : "+v"(part) : "v"(kv.w), "v"(qp.w));
        part += __shfl_xor(part, 1, 64);
        part += __shfl_xor(part, 2, 64);
        part += __shfl_xor(part, 4, 64);
        sc[f] = ok ? part * 0.125f : -1e30f;
    }

    float mx = sc[0];
#pragma unroll
    for (int f = 1; f < NF; ++f) mx = fmaxf(mx, sc[f]);
    float den = 0.f;
#pragma unroll
    for (int f = 0; f < NF; ++f) { sc[f] = __expf(sc[f] - mx); den += sc[f]; }

    float o[8];
#pragma unroll
    for (int e = 0; e < 8; ++e) o[e] = 0.f;
#pragma unroll
    for (int f = 0; f < NF; ++f) {
        if (fib[f] > smax) continue;                        // wave-uniform skip
        const int sk = (fib[f] <= s) ? s - fib[f] : s;
        bf16x8 vv = *(const bf16x8*)(Vp + ((size_t)sk << 6) + c * 8);
        const float w = sc[f];
#pragma unroll
        for (int e = 0; e < 8; ++e) o[e] += w * bf2f(vv[e]);
    }

    const float inv = 1.f / den;
    short8 r;
#pragma unroll
    for (int e = 0; e < 8; ++e) r[e] = f2bf(o[e] * inv);
    *(short8*)(attn + (size_t)(b * SS + s) * DIM + h * HD + c * 8) = r;
}

extern "C" void kernel_launch(void* const* d_in, const int* in_sizes, int n_in,
                              void* d_out, int out_size, void* d_ws, size_t ws_size,
                              hipStream_t stream)
{
    const float* x     = (const float*)d_in[0];
    const float* w_qkv = (const float*)d_in[1];
    const float* b_qkv = (const float*)d_in[2];
    const float* w_out = (const float*)d_in[3];
    const float* b_out = (const float*)d_in[4];
    float* out = (float*)d_out;

    short* qkvh  = (short*)d_ws;                              // [3][2][12][2048][64] bf16
    short* attnb = (short*)((char*)d_ws + 18874368);          // [4096][768] bf16
    short* xb    = (short*)((char*)d_ws + 25165824);          // [4096][768] bf16
    short* wqkvb = (short*)((char*)d_ws + 31457280);          // [2304][768] bf16
    short* woutb = (short*)((char*)d_ws + 34996224);          // [768][768]  bf16

    conv_kernel<<<dim3(2688, 1, 1), dim3(256, 1, 1), 0, stream>>>(
        x, xb, w_qkv, wqkvb, w_out, woutb);

    gemm_qkv_kernel<<<dim3(QKVN / 128, MM / 128, 1), dim3(512, 1, 1), 0, stream>>>(
        xb, wqkvb, b_qkv, qkvh);

    fib_attn_kernel<<<dim3(1536, 1, 1), dim3(256, 1, 1), 0, stream>>>(qkvh, attnb);

    gemm_out_kernel<<<dim3(DIM / 128, MM / 64, 1), dim3(512, 1, 1), 0, stream>>>(
        attnb, woutb, b_out, out);
}

// Round 16
// 58.034 us; speedup vs baseline: 1.0266x; 1.0266x over previous
//
#include <hip/hip_runtime.h>
#include <hip/hip_bf16.h>

#define DIM   768
#define NH    12
#define HD    64
#define BB    2
#define SS    2048
#define QKVN  (3 * DIM)   // 2304
#define MM    (BB * SS)   // 4096

typedef __attribute__((ext_vector_type(8))) short bf16x8;
typedef __attribute__((ext_vector_type(8))) short short8;
typedef __attribute__((ext_vector_type(4))) float f32x4;

__device__ __forceinline__ short f2bf(float f) {
    unsigned int u = __float_as_uint(f);
    unsigned int r = (u + 0x7FFFu + ((u >> 16) & 1u)) >> 16;
    return (short)r;
}
__device__ __forceinline__ float bf2f(short s) {
    return __uint_as_float((unsigned int)(unsigned short)s << 16);
}

__device__ __forceinline__ void gld16(const short* g, short* l) {
    __builtin_amdgcn_global_load_lds(
        (const __attribute__((address_space(1))) void*)g,
        (__attribute__((address_space(3))) void*)l, 16, 0, 0);
}

template<int N> __device__ __forceinline__ void waitvm() {
    if constexpr (N == 0) asm volatile("s_waitcnt vmcnt(0)" ::: "memory");
    else if constexpr (N == 3) asm volatile("s_waitcnt vmcnt(3)" ::: "memory");
    else if constexpr (N == 4) asm volatile("s_waitcnt vmcnt(4)" ::: "memory");
}

// fp32 -> bf16 conversion for x, w_qkv, w_out (R8-exact)
__global__ __launch_bounds__(256) void conv_kernel(
    const float* __restrict__ x,  short* __restrict__ xb,
    const float* __restrict__ wq, short* __restrict__ wqb,
    const float* __restrict__ wo, short* __restrict__ wob)
{
    const int nx = (MM * DIM) / 8;
    const int nq = (QKVN * DIM) / 8;
    int i8 = blockIdx.x * 256 + threadIdx.x;
    const float* src; short* dst;
    if (i8 < nx)           { src = x;  dst = xb; }
    else if (i8 < nx + nq) { i8 -= nx; src = wq; dst = wqb; }
    else                   { i8 -= nx + nq; src = wo; dst = wob; }
    const float4* p = (const float4*)src + (size_t)i8 * 2;
    float4 a = p[0], b = p[1];
    short8 r;
    r[0] = f2bf(a.x); r[1] = f2bf(a.y); r[2] = f2bf(a.z); r[3] = f2bf(a.w);
    r[4] = f2bf(b.x); r[5] = f2bf(b.y); r[6] = f2bf(b.z); r[7] = f2bf(b.w);
    *((short8*)dst + i8) = r;
}

// ------------- GEMM core: counted-vmcnt 2-buffer pipeline (R8-exact) -----

template<int RT>
__device__ __forceinline__ void stage_op(const short* gb, int K, int k0, short* ld)
{
#pragma unroll
    for (int ii = 0; ii < RT / 64; ++ii)
        gld16(gb + (size_t)(64 * ii) * K + k0, ld + ii * 4096);
}

template<int MF, int NF>
__device__ __forceinline__ void read_frags(
    const short* lsA, const short* lsB, int arow, int brow, int kg, int sw,
    bf16x8 af[2][MF], bf16x8 bfr[2][NF])
{
#pragma unroll
    for (int kk = 0; kk < 2; ++kk) {
        const int ko = (kk * 32 + kg * 8) ^ sw;
#pragma unroll
        for (int i = 0; i < MF; ++i)
            af[kk][i] = *(const bf16x8*)&lsA[(arow + i * 16) * 64 + ko];
#pragma unroll
        for (int j = 0; j < NF; ++j)
            bfr[kk][j] = *(const bf16x8*)&lsB[(brow + j * 16) * 64 + ko];
    }
}

template<int MF, int NF>
__device__ __forceinline__ void mfma_frags(
    bf16x8 af[2][MF], bf16x8 bfr[2][NF], f32x4 acc[MF][NF])
{
#pragma unroll
    for (int kk = 0; kk < 2; ++kk)
#pragma unroll
        for (int i = 0; i < MF; ++i)
#pragma unroll
            for (int j = 0; j < NF; ++j)
                acc[i][j] = __builtin_amdgcn_mfma_f32_16x16x32_bf16(
                    af[kk][i], bfr[kk][j], acc[i][j], 0, 0, 0);
}

template<int MF, int NF, int ART, int BRT, int VC>
__device__ __forceinline__ void phase_steady(
    const short* lsA, const short* lsB, short* ldA, short* ldB,
    const short* Ab, const short* Bb, int K, int knext,
    int arow, int brow, int kg, int sw, f32x4 acc[MF][NF])
{
    bf16x8 af[2][MF], bfr[2][NF];
    read_frags<MF, NF>(lsA, lsB, arow, brow, kg, sw, af, bfr);
    asm volatile("s_waitcnt lgkmcnt(0)" ::: "memory");
    __builtin_amdgcn_s_barrier();
    stage_op<ART>(Ab, K, knext, ldA);
    stage_op<BRT>(Bb, K, knext, ldB);
    mfma_frags<MF, NF>(af, bfr, acc);
    waitvm<VC>();
    __builtin_amdgcn_s_barrier();
}

// GEMM1: BM=128, BN=128, 512 thr (8 waves 2x4), MF=4, NF=2. K=768 (NT=12).
__global__ __launch_bounds__(512) void gemm_qkv_kernel(
    const short* __restrict__ A, const short* __restrict__ Bm,
    const float* __restrict__ bias, short* __restrict__ qkvh)
{
    constexpr int K = DIM, NT = 12;
    __shared__ short lsA0[8192], lsB0[8192], lsA1[8192], lsB1[8192];

    const int t    = threadIdx.x;
    const int lane = t & 63;
    const int wid  = t >> 6;
    const int wrow = wid >> 2, wcol = wid & 3;
    const int l16  = lane & 15;
    const int kg   = lane >> 4;
    const int row0 = blockIdx.y * 128;
    const int col0 = blockIdx.x * 128;

    const int srow = t >> 3;
    const int scol = ((t & 7) ^ (srow & 7)) * 8;
    const short* Ab = A  + (size_t)(row0 + srow) * K + scol;
    const short* Bb = Bm + (size_t)(col0 + srow) * K + scol;
    short* ldA0 = lsA0 + t * 8;  short* ldB0 = lsB0 + t * 8;
    short* ldA1 = lsA1 + t * 8;  short* ldB1 = lsB1 + t * 8;
    const int arow = wrow * 64 + l16;
    const int brow = wcol * 32 + l16;
    const int sw   = (l16 & 7) * 8;

    f32x4 acc[4][2];
#pragma unroll
    for (int i = 0; i < 4; ++i)
#pragma unroll
        for (int j = 0; j < 2; ++j) acc[i][j] = (f32x4){0.f, 0.f, 0.f, 0.f};

    stage_op<128>(Ab, K, 0, ldA0);
    stage_op<128>(Bb, K, 0, ldB0);
    stage_op<128>(Ab, K, 64, ldA1);
    stage_op<128>(Bb, K, 64, ldB1);
    waitvm<4>();
    __builtin_amdgcn_s_barrier();

#pragma unroll
    for (int kt = 0; kt < NT - 2; kt += 2) {
        phase_steady<4, 2, 128, 128, 4>(lsA0, lsB0, ldA0, ldB0, Ab, Bb, K,
                                        (kt + 2) * 64, arow, brow, kg, sw, acc);
        phase_steady<4, 2, 128, 128, 4>(lsA1, lsB1, ldA1, ldB1, Ab, Bb, K,
                                        (kt + 3) * 64, arow, brow, kg, sw, acc);
    }
    {
        bf16x8 af[2][4], bfr[2][2];
        read_frags<4, 2>(lsA0, lsB0, arow, brow, kg, sw, af, bfr);
        mfma_frags<4, 2>(af, bfr, acc);
        waitvm<0>();
        __builtin_amdgcn_s_barrier();
        read_frags<4, 2>(lsA1, lsB1, arow, brow, kg, sw, af, bfr);
        mfma_frags<4, 2>(af, bfr, acc);
    }

#pragma unroll
    for (int j = 0; j < 2; ++j) {
        const int col = col0 + wcol * 32 + j * 16 + l16;
        const int ty = col / DIM;
        const int hh = (col % DIM) >> 6;
        const int dd = col & 63;
        const float bv = bias[col];
        const size_t cbase = ((size_t)(ty * BB * NH) * SS) * HD;
#pragma unroll
        for (int i = 0; i < 4; ++i) {
            const int rbase = row0 + wrow * 64 + i * 16 + kg * 4;
#pragma unroll
            for (int r = 0; r < 4; ++r) {
                const int row = rbase + r;
                const int bq = row >> 11, sq = row & 2047;
                qkvh[cbase + (((size_t)(bq * NH + hh) * SS + sq) << 6) + dd] =
                    f2bf(acc[i][j][r] + bv);
            }
        }
    }
}

// GEMM2: BM=64, BN=128, 512 thr, MF=2, NF=2 (grid 6x64=384). NT=12. R8-exact.
__global__ __launch_bounds__(512) void gemm_out_kernel(
    const short* __restrict__ A, const short* __restrict__ Bm,
    const float* __restrict__ bias, float* __restrict__ C)
{
    constexpr int K = DIM, N = DIM, NT = 12;
    __shared__ short lsA0[4096], lsB0[8192], lsA1[4096], lsB1[8192];

    const int t    = threadIdx.x;
    const int lane = t & 63;
    const int wid  = t >> 6;
    const int wrow = wid >> 2, wcol = wid & 3;
    const int l16  = lane & 15;
    const int kg   = lane >> 4;
    const int row0 = blockIdx.y * 64;
    const int col0 = blockIdx.x * 128;

    const int srow = t >> 3;
    const int scol = ((t & 7) ^ (srow & 7)) * 8;
    const short* Ab = A  + (size_t)(row0 + srow) * K + scol;
    const short* Bb = Bm + (size_t)(col0 + srow) * K + scol;
    short* ldA0 = lsA0 + t * 8;  short* ldB0 = lsB0 + t * 8;
    short* ldA1 = lsA1 + t * 8;  short* ldB1 = lsB1 + t * 8;
    const int arow = wrow * 32 + l16;
    const int brow = wcol * 32 + l16;
    const int sw   = (l16 & 7) * 8;

    f32x4 acc[2][2];
#pragma unroll
    for (int i = 0; i < 2; ++i)
#pragma unroll
        for (int j = 0; j < 2; ++j) acc[i][j] = (f32x4){0.f, 0.f, 0.f, 0.f};

    stage_op<64>(Ab, K, 0, ldA0);
    stage_op<128>(Bb, K, 0, ldB0);
    stage_op<64>(Ab, K, 64, ldA1);
    stage_op<128>(Bb, K, 64, ldB1);
    waitvm<3>();
    __builtin_amdgcn_s_barrier();

#pragma unroll
    for (int kt = 0; kt < NT - 2; kt += 2) {
        phase_steady<2, 2, 64, 128, 3>(lsA0, lsB0, ldA0, ldB0, Ab, Bb, K,
                                       (kt + 2) * 64, arow, brow, kg, sw, acc);
        phase_steady<2, 2, 64, 128, 3>(lsA1, lsB1, ldA1, ldB1, Ab, Bb, K,
                                       (kt + 3) * 64, arow, brow, kg, sw, acc);
    }
    {
        bf16x8 af[2][2], bfr[2][2];
        read_frags<2, 2>(lsA0, lsB0, arow, brow, kg, sw, af, bfr);
        mfma_frags<2, 2>(af, bfr, acc);
        waitvm<0>();
        __builtin_amdgcn_s_barrier();
        read_frags<2, 2>(lsA1, lsB1, arow, brow, kg, sw, af, bfr);
        mfma_frags<2, 2>(af, bfr, acc);
    }

#pragma unroll
    for (int j = 0; j < 2; ++j) {
        const int col = col0 + wcol * 32 + j * 16 + l16;
        const float bv = bias[col];
#pragma unroll
        for (int i = 0; i < 2; ++i) {
            const int rbase = row0 + wrow * 32 + i * 16 + kg * 4;
#pragma unroll
            for (int r = 0; r < 4; ++r)
                C[(size_t)(rbase + r) * N + col] = acc[i][j][r] + bv;
        }
    }
}

// Sparse Fibonacci attention — R14-exact: wave = 8 q, 8 lanes/q, K-dot via
// v_dot2_f32_bf16 (packed, no cvt), two-pass, no branches in the row loop
// (R15's wave-uniform skip regressed: it fragmented the pipelined load stream).
__global__ __launch_bounds__(256) void fib_attn_kernel(
    const short* __restrict__ qkvh, short* __restrict__ attn)
{
    const int idx   = blockIdx.x;          // [0,1536)
    const int j     = idx >> 3;            // [0,192)
    const int bh    = (idx & 7) + 8 * (j >> 6);   // [0,24), pinned per XCD
    const int chunk = j & 63;              // [0,64)
    const int wid   = threadIdx.x >> 6;
    const int lane  = threadIdx.x & 63;
    const int ql    = lane >> 3;
    const int c     = lane & 7;
    const int s     = chunk * 32 + wid * 8 + ql;
    const int b = bh / NH, h = bh % NH;

    constexpr size_t TYB = (size_t)BB * NH * SS * HD;
    const size_t base = ((size_t)bh * SS) << 6;
    const short* Kp = qkvh + TYB + base;
    const short* Vp = qkvh + 2 * TYB + base;

    // q as 4 packed bf16-pair words (feeds dot2 directly)
    const int4 qp = *(const int4*)(qkvh + base + ((size_t)s << 6) + c * 8);

    constexpr int NF = 17;
    const int fib[NF] = {0, 1, 2, 3, 5, 8, 13, 21, 34, 55, 89, 144,
                         233, 377, 610, 987, 1597};
    float sc[NF];
#pragma unroll
    for (int f = 0; f < NF; ++f) {
        const bool ok = (fib[f] <= s);
        const int sk = ok ? s - fib[f] : s;
        const int4 kv = *(const int4*)(Kp + ((size_t)sk << 6) + c * 8);
        float part = 0.f;
        asm("v_dot2_f32_bf16 %0, %1, %2, %0" : "+v"(part) : "v"(kv.x), "v"(qp.x));
        asm("v_dot2_f32_bf16 %0, %1, %2, %0" : "+v"(part) : "v"(kv.y), "v"(qp.y));
        asm("v_dot2_f32_bf16 %0, %1, %2, %0" : "+v"(part) : "v"(kv.z), "v"(qp.z));
        asm("v_dot2_f32_bf16 %0, %1, %2, %0" : "+v"(part) : "v"(kv.w), "v"(qp.w));
        part += __shfl_xor(part, 1, 64);
        part += __shfl_xor(part, 2, 64);
        part += __shfl_xor(part, 4, 64);
        sc[f] = ok ? part * 0.125f : -1e30f;
    }

    float mx = sc[0];
#pragma unroll
    for (int f = 1; f < NF; ++f) mx = fmaxf(mx, sc[f]);
    float den = 0.f;
#pragma unroll
    for (int f = 0; f < NF; ++f) { sc[f] = __expf(sc[f] - mx); den += sc[f]; }

    float o[8];
#pragma unroll
    for (int e = 0; e < 8; ++e) o[e] = 0.f;
#pragma unroll
    for (int f = 0; f < NF; ++f) {
        const int sk = (fib[f] <= s) ? s - fib[f] : s;
        bf16x8 vv = *(const bf16x8*)(Vp + ((size_t)sk << 6) + c * 8);
        const float w = sc[f];
#pragma unroll
        for (int e = 0; e < 8; ++e) o[e] += w * bf2f(vv[e]);
    }

    const float inv = 1.f / den;
    short8 r;
#pragma unroll
    for (int e = 0; e < 8; ++e) r[e] = f2bf(o[e] * inv);
    *(short8*)(attn + (size_t)(b * SS + s) * DIM + h * HD + c * 8) = r;
}

extern "C" void kernel_launch(void* const* d_in, const int* in_sizes, int n_in,
                              void* d_out, int out_size, void* d_ws, size_t ws_size,
                              hipStream_t stream)
{
    const float* x     = (const float*)d_in[0];
    const float* w_qkv = (const float*)d_in[1];
    const float* b_qkv = (const float*)d_in[2];
    const float* w_out = (const float*)d_in[3];
    const float* b_out = (const float*)d_in[4];
    float* out = (float*)d_out;

    short* qkvh  = (short*)d_ws;                              // [3][2][12][2048][64] bf16
    short* attnb = (short*)((char*)d_ws + 18874368);          // [4096][768] bf16
    short* xb    = (short*)((char*)d_ws + 25165824);          // [4096][768] bf16
    short* wqkvb = (short*)((char*)d_ws + 31457280);          // [2304][768] bf16
    short* woutb = (short*)((char*)d_ws + 34996224);          // [768][768]  bf16

    conv_kernel<<<dim3(2688, 1, 1), dim3(256, 1, 1), 0, stream>>>(
        x, xb, w_qkv, wqkvb, w_out, woutb);

    gemm_qkv_kernel<<<dim3(QKVN / 128, MM / 128, 1), dim3(512, 1, 1), 0, stream>>>(
        xb, wqkvb, b_qkv, qkvh);

    fib_attn_kernel<<<dim3(1536, 1, 1), dim3(256, 1, 1), 0, stream>>>(qkvh, attnb);

    gemm_out_kernel<<<dim3(DIM / 128, MM / 64, 1), dim3(512, 1, 1), 0, stream>>>(
        attnb, woutb, b_out, out);
}